// Round 24
// baseline (136.867 us; speedup 1.0000x reference)
//
#include <hip/hip_runtime.h>
#include <hip/hip_bf16.h>
#include <math.h>

#define N_ 8
#define L_ 8192
#define C_ 256
#define H_ 4
#define D_ 64
#define NH_ (N_*H_)
#define NCH 32
#define CHUNK (L_/NCH)           // 256
#define Q_ ((size_t)N_*H_*L_*D_) // 16,777,216 elements per tensor

typedef float f32x4 __attribute__((ext_vector_type(4)));
typedef short short8 __attribute__((ext_vector_type(8)));

// bf16 helpers ---------------------------------------------------------------
__device__ inline ushort f2b(float f){
  uint x = __float_as_uint(f);
  uint r = (x + 0x7fffu + ((x >> 16) & 1u)) >> 16;
  return (ushort)r;
}
__device__ inline ushort f2b_hw(float f){
  __hip_bfloat16 h = __float2bfloat16(f);
  return *reinterpret_cast<ushort*>(&h);
}
__device__ inline float b2f(ushort u){
  return __uint_as_float(((uint)u) << 16);
}
__device__ inline uint pk2h(float a, float b){
  return (uint)f2b_hw(a) | ((uint)f2b_hw(b) << 16);
}

#define GLD16(g, l) __builtin_amdgcn_global_load_lds( \
    (const __attribute__((address_space(1))) void*)(g), \
    (__attribute__((address_space(3))) void*)(l), 16, 0, 0)

// ---------------------------------------------------------------------------
// K0: fp32 -> bf16 convert for BOTH weight matrices in one launch.
// ---------------------------------------------------------------------------
__global__ __launch_bounds__(256) void conv_both(const float* __restrict__ w1,
                                                 ushort* __restrict__ wb1,
                                                 const float* __restrict__ w2,
                                                 ushort* __restrict__ wb2) {
  const int b = blockIdx.x;
  const float* src; ushort* dst; int i;
  if (b < 192) { src = w1; dst = wb1; i = (b*256 + threadIdx.x) * 4; }
  else         { src = w2; dst = wb2; i = ((b-192)*256 + threadIdx.x) * 4; }
  float4 f = *(const float4*)(src + i);
  *(ushort4*)&dst[i] = make_ushort4(f2b(f.x), f2b(f.y), f2b(f.z), f2b(f.w));
}

// ---------------------------------------------------------------------------
// K1: qkv = x @ wb^T via bf16 MFMA (best-measured version, banked; 84 us).
// BM=128, BN=256, 8 waves (2M x 4N); fused fp32->bf16 A reg-staging with
// one-iteration prefetch; B via global_load_lds (rule-21 swizzle);
// XCD-chunked 1-D grid (1536 = 512 m-tiles x 3); verified epilogue.
// Measured worse: BN/2 (94), BM/2 (126), split-cvt (+20 e2e), barrier-free
// (104), LDS epilogue (+15%), setprio (+8), prefetch variants null.
// ---------------------------------------------------------------------------
__global__ __launch_bounds__(512) void qkv_gemm_mfma2(const float* __restrict__ x,
                                                      const ushort* __restrict__ wb,
                                                      const int* __restrict__ mask,
                                                      ushort* __restrict__ qb,
                                                      ushort* __restrict__ kb,
                                                      ushort* __restrict__ vb) {
  __shared__ ushort As[128][64];
  __shared__ ushort Bs[256][64];
  const int tid  = threadIdx.x;
  const int lane = tid & 63;
  const int wid  = tid >> 6, wm = wid >> 2, wn = wid & 3;
  const int r15  = lane & 15, kg = lane >> 4;
  const int lrow8 = lane >> 3;
  const int lgrp  = lane & 7;
  const int bid = blockIdx.x;
  const int wg  = (bid & 7)*192 + (bid >> 3);   // bijective XCD chunk swizzle
  const int bx  = wg / 3, by = wg % 3;
  const int gm0 = bx * 128;
  const int gn0 = by * 256;

  const int arow = tid >> 2;              // 0..127
  const int ag0  = (tid & 3) << 1;        // first 8-col group: 0,2,4,6
  const float* asrc = x + (size_t)(gm0 + arow)*C_ + (ag0 << 3);

  f32x4 acc[4][4] = {};

  float4 cf0 = *(const float4*)(asrc);
  float4 cf1 = *(const float4*)(asrc + 4);
  float4 cf2 = *(const float4*)(asrc + 8);
  float4 cf3 = *(const float4*)(asrc + 12);

#pragma unroll
  for (int k0 = 0; k0 < C_; k0 += 64) {
    float4 nf0, nf1, nf2, nf3;
    if (k0 < C_ - 64) {
      nf0 = *(const float4*)(asrc + k0 + 64);
      nf1 = *(const float4*)(asrc + k0 + 68);
      nf2 = *(const float4*)(asrc + k0 + 72);
      nf3 = *(const float4*)(asrc + k0 + 76);
    }
    if (k0) __syncthreads();
#pragma unroll
    for (int r = 0; r < 4; ++r) {
      const int row = wid*32 + r*8 + lrow8;
      const int gc  = k0 + ((lgrp ^ (row & 7)) << 3);
      GLD16(wb + (size_t)(gn0 + row)*C_ + gc, &Bs[wid*32 + r*8][0]);
    }
    {
      uint4 p0 = make_uint4(pk2h(cf0.x,cf0.y), pk2h(cf0.z,cf0.w),
                            pk2h(cf1.x,cf1.y), pk2h(cf1.z,cf1.w));
      uint4 p1 = make_uint4(pk2h(cf2.x,cf2.y), pk2h(cf2.z,cf2.w),
                            pk2h(cf3.x,cf3.y), pk2h(cf3.z,cf3.w));
      *(uint4*)&As[arow][( ag0      ^ (arow & 7)) << 3] = p0;
      *(uint4*)&As[arow][((ag0 + 1) ^ (arow & 7)) << 3] = p1;
    }
    __syncthreads();
#pragma unroll
    for (int ks = 0; ks < 2; ++ks) {
      short8 a[4], b[4];
#pragma unroll
      for (int mi = 0; mi < 4; ++mi) {
        const int row = wm*64 + mi*16 + r15;
        a[mi] = *(const short8*)&As[row][((ks*4 + kg) ^ (row & 7)) << 3];
      }
#pragma unroll
      for (int ni = 0; ni < 4; ++ni) {
        const int row = wn*64 + ni*16 + r15;
        b[ni] = *(const short8*)&Bs[row][((ks*4 + kg) ^ (row & 7)) << 3];
      }
#pragma unroll
      for (int mi = 0; mi < 4; ++mi)
#pragma unroll
        for (int ni = 0; ni < 4; ++ni)
          acc[mi][ni] = __builtin_amdgcn_mfma_f32_16x16x32_bf16(
              a[mi], b[ni], acc[mi][ni], 0, 0, 0);
    }
    if (k0 < C_ - 64) { cf0 = nf0; cf1 = nf1; cf2 = nf2; cf3 = nf3; }
  }

  const int sh = by*4 + wn;
  const int s = sh >> 2, h = sh & 3;
  ushort* dst = (s == 0) ? qb : (s == 1) ? kb : vb;
#pragma unroll
  for (int mi = 0; mi < 4; ++mi) {
    const int rbase = gm0 + wm*64 + mi*16 + (kg << 2);
#pragma unroll
    for (int j = 0; j < 4; ++j) {
      const int gr = rbase + j;
      const int nn = gr >> 13, l = gr & (L_-1);
      float v0 = acc[mi][0][j], v1 = acc[mi][1][j],
            v2 = acc[mi][2][j], v3 = acc[mi][3][j];
      if (s < 2) {
        float ss = v0*v0 + v1*v1 + v2*v2 + v3*v3;
        ss += __shfl_xor(ss, 1); ss += __shfl_xor(ss, 2);
        ss += __shfl_xor(ss, 4); ss += __shfl_xor(ss, 8);
        const float inv = 1.0f / sqrtf(ss);
        v0 *= inv; v1 *= inv; v2 *= inv; v3 *= inv;
      }
      const bool masked = (s == 0) && (mask[(size_t)nn*L_ + l] == 0);
      const size_t base = (((size_t)nn*H_ + h)*L_ + l)*D_ + r15;
      if (masked) {
        const ushort mb = 0xBE00u;  // bf16(-0.125)
        dst[base] = mb; dst[base+16] = mb; dst[base+32] = mb; dst[base+48] = mb;
      } else {
        dst[base]    = f2b(v0); dst[base+16] = f2b(v1);
        dst[base+32] = f2b(v2); dst[base+48] = f2b(v3);
      }
    }
  }
}

// ---------------------------------------------------------------------------
// K3 (MFMA): per (n,h,chunk): kv[d][e] = sum_l k[l][d] v[l][e].
// ---------------------------------------------------------------------------
__global__ __launch_bounds__(256, 8) void kv_partial(const ushort* __restrict__ kb,
                                                     const ushort* __restrict__ vb,
                                                     ushort* __restrict__ part) {
  const int nh = blockIdx.x, ch = blockIdx.y;
  const size_t base = ((size_t)nh*L_ + (size_t)ch*CHUNK) * 64;
  __shared__ ushort ks[32][68];
  __shared__ ushort vs[32][68];
  const int tid = threadIdx.x;
  const int lane = tid & 63;
  const int w = tid >> 6;
  const int r15 = lane & 15, kg = lane >> 4;
  const int lr = tid >> 3, lc = (tid & 7) << 3;
  f32x4 acc[4] = {};

  for (int l0 = 0; l0 < CHUNK; l0 += 32) {
    if (l0) __syncthreads();
    *(uint4*)&ks[lr][lc] = *(const uint4*)(kb + base + (size_t)(l0+lr)*64 + lc);
    *(uint4*)&vs[lr][lc] = *(const uint4*)(vb + base + (size_t)(l0+lr)*64 + lc);
    __syncthreads();
    short8 a;
#pragma unroll
    for (int j = 0; j < 8; ++j) a[j] = (short)ks[kg*8 + j][w*16 + r15];
#pragma unroll
    for (int ni = 0; ni < 4; ++ni) {
      short8 b;
#pragma unroll
      for (int j = 0; j < 8; ++j) b[j] = (short)vs[kg*8 + j][ni*16 + r15];
      acc[ni] = __builtin_amdgcn_mfma_f32_16x16x32_bf16(a, b, acc[ni], 0, 0, 0);
    }
  }
  ushort* P = part + ((size_t)nh*NCH + ch)*4096;
#pragma unroll
  for (int ni = 0; ni < 4; ++ni)
#pragma unroll
    for (int j = 0; j < 4; ++j)
      P[(w*16 + kg*4 + j)*64 + ni*16 + r15] = f2b(acc[ni][j]);
}

// ---------------------------------------------------------------------------
// K4: reduce bf16 partials (fp32 accum), fold 1/pi, write kvbT[e][d] bf16.
// ---------------------------------------------------------------------------
__global__ __launch_bounds__(256) void kv_reduce(const ushort* __restrict__ part,
                                                 ushort* __restrict__ kvbT) {
  const int nh = blockIdx.x;
  const int i0 = blockIdx.y*1024 + threadIdx.x*4;
  float s0 = 0.f, s1 = 0.f, s2 = 0.f, s3 = 0.f;
#pragma unroll
  for (int c = 0; c < NCH; ++c) {
    ushort4 p = *(const ushort4*)(part + ((size_t)nh*NCH + c)*4096 + i0);
    s0 += b2f(p.x); s1 += b2f(p.y); s2 += b2f(p.z); s3 += b2f(p.w);
  }
  const float ip = 0.31830988618379067f;
  const float r[4] = {s0*ip, s1*ip, s2*ip, s3*ip};
#pragma unroll
  for (int j = 0; j < 4; ++j) {
    const int i = i0 + j;
    const int d = i >> 6, e = i & 63;
    kvbT[(size_t)nh*4096 + e*64 + d] = f2b(r[j]);
  }
}

// ---------------------------------------------------------------------------
// K5: MFMA attn+proj, 32-row tiles (best-measured version, banked).
// ---------------------------------------------------------------------------
__global__ __launch_bounds__(256, 4) void attn_proj3(const ushort* __restrict__ qb,
                                                     const ushort* __restrict__ vb,
                                                     const ushort* __restrict__ kvbT,
                                                     const float* __restrict__ dwc,
                                                     const ushort* __restrict__ pwb,
                                                     const float* __restrict__ pb,
                                                     float* __restrict__ out) {
  __shared__ ushort vsm[4][40][72];   // 23040 B (rows l0-4 .. l0+35)
  __shared__ ushort attn_s[32][260];  // 16640 B
  const int tid = threadIdx.x;
  const int lane = tid & 63;
  const int w = tid >> 6;
  const int r15 = lane & 15, kg = lane >> 4;
  const int n = blockIdx.y;
  const int l0 = blockIdx.x * 32;

  for (int f = tid; f < 1280; f += 256) {
    const int h = f / 320, rem = f % 320;
    const int row = rem >> 3, c0 = (rem & 7) << 3;
    const int lg = l0 - 4 + row;
    uint4 val = make_uint4(0,0,0,0);
    if ((unsigned)lg < (unsigned)L_)
      val = *(const uint4*)(vb + (((size_t)(n*4+h)*L_ + lg) << 6) + c0);
    *(uint4*)&vsm[h][row][c0] = val;
  }

  const int nh = n*4 + w;
  f32x4 acc[2][4] = {};
  {
    const ushort* qbase = qb + ((size_t)nh*L_ + l0)*64;
    const ushort* kvb = kvbT + (size_t)nh*4096;
#pragma unroll
    for (int ks = 0; ks < 2; ++ks) {
      const int kofs = ks*32 + kg*8;
      short8 a[2], b[4];
#pragma unroll
      for (int mi = 0; mi < 2; ++mi)
        a[mi] = *(const short8*)(qbase + (size_t)(mi*16 + r15)*64 + kofs);
#pragma unroll
      for (int ni = 0; ni < 4; ++ni)
        b[ni] = *(const short8*)(kvb + (ni*16 + r15)*64 + kofs);
#pragma unroll
      for (int mi = 0; mi < 2; ++mi)
#pragma unroll
        for (int ni = 0; ni < 4; ++ni)
          acc[mi][ni] = __builtin_amdgcn_mfma_f32_16x16x32_bf16(
              a[mi], b[ni], acc[mi][ni], 0, 0, 0);
    }
  }
  __syncthreads();   // vsm staged

  {
    float wcv[9];
#pragma unroll
    for (int j = 0; j < 9; ++j) wcv[j] = dwc[w*9 + j];
    float win[9];
#pragma unroll
    for (int j = 0; j < 9; ++j) win[j] = b2f(vsm[w][j][lane]);
#pragma unroll
    for (int r = 0; r < 32; ++r) {
      float cv = 0.f;
#pragma unroll
      for (int j = 0; j < 9; ++j) cv += win[j] * wcv[j];
      attn_s[r][w*64 + lane] = f2b(cv);
      if (r < 31) {
#pragma unroll
        for (int j = 0; j < 8; ++j) win[j] = win[j+1];
        win[8] = b2f(vsm[w][r + 9][lane]);
      }
    }
  }
  // NO barrier: norm phase touches only this wave's own attn_s columns.

#pragma unroll
  for (int mi = 0; mi < 2; ++mi) {
#pragma unroll
    for (int j = 0; j < 4; ++j) {
      const int r = mi*16 + kg*4 + j;
      float t[4];
#pragma unroll
      for (int ni = 0; ni < 4; ++ni) {
        const int e = ni*16 + r15;
        t[ni] = acc[mi][ni][j] + 0.5f * b2f(vsm[w][r+4][e]);
      }
      float ss = t[0]*t[0] + t[1]*t[1] + t[2]*t[2] + t[3]*t[3];
      ss += __shfl_xor(ss, 1); ss += __shfl_xor(ss, 2);
      ss += __shfl_xor(ss, 4); ss += __shfl_xor(ss, 8);
      const float inv = 1.0f / sqrtf(ss);
#pragma unroll
      for (int ni = 0; ni < 4; ++ni) {
        const int e = ni*16 + r15;
        const float cv = b2f(attn_s[r][w*64 + e]);
        attn_s[r][w*64 + e] = f2b(t[ni]*inv + cv);
      }
    }
  }
  __syncthreads();   // attn tile final

  f32x4 acc2[2][4] = {};
  const ushort* pwq = pwb + (size_t)(w*64)*256;
#pragma unroll
  for (int ks = 0; ks < 8; ++ks) {
    const int kofs = ks*32 + kg*8;
    short8 a[2], b[4];
#pragma unroll
    for (int mi = 0; mi < 2; ++mi)
      a[mi] = *(const short8*)&attn_s[mi*16 + r15][kofs];
#pragma unroll
    for (int ni = 0; ni < 4; ++ni)
      b[ni] = *(const short8*)(pwq + (size_t)(ni*16 + r15)*256 + kofs);
#pragma unroll
    for (int mi = 0; mi < 2; ++mi)
#pragma unroll
      for (int ni = 0; ni < 4; ++ni)
        acc2[mi][ni] = __builtin_amdgcn_mfma_f32_16x16x32_bf16(
            a[mi], b[ni], acc2[mi][ni], 0, 0, 0);
  }
#pragma unroll
  for (int ni = 0; ni < 4; ++ni) {
    const int o = w*64 + ni*16 + r15;
    const float bias = pb[o];
#pragma unroll
    for (int mi = 0; mi < 2; ++mi) {
#pragma unroll
      for (int j = 0; j < 4; ++j) {
        const int l = l0 + mi*16 + kg*4 + j;
        out[((size_t)n*L_ + l)*C_ + o] = acc2[mi][ni][j] + bias;
      }
    }
  }
}

extern "C" void kernel_launch(void* const* d_in, const int* in_sizes, int n_in,
                              void* d_out, int out_size, void* d_ws, size_t ws_size,
                              hipStream_t stream) {
  const float* x      = (const float*)d_in[0];
  const int*   mask   = (const int*)d_in[1];
  const float* qkv_w  = (const float*)d_in[2];
  const float* proj_w = (const float*)d_in[3];
  const float* proj_b = (const float*)d_in[4];
  const float* dconv_w= (const float*)d_in[5];
  float* out = (float*)d_out;

  // ws: q/k/v bf16 (96 MB) + part bf16 (8 MB) + weights (<1 MB)
  ushort* qb = (ushort*)d_ws;
  ushort* kb = qb + Q_;
  ushort* vb = kb + Q_;
  ushort* part = vb + Q_;                          // NH_*NCH*4096 bf16 = 8 MB
  ushort* kvbT = part + (size_t)NH_*NCH*4096;
  ushort* wb   = kvbT + (size_t)NH_*4096;
  ushort* pwb  = wb + 768*256;

  conv_both     <<<dim3(256),       256, 0, stream>>>(qkv_w, wb, proj_w, pwb);
  qkv_gemm_mfma2<<<dim3(1536),      512, 0, stream>>>(x, wb, mask, qb, kb, vb);
  kv_partial    <<<dim3(NH_, NCH),  256, 0, stream>>>(kb, vb, part);
  kv_reduce     <<<dim3(NH_, 4),    256, 0, stream>>>(part, kvbT);
  attn_proj3    <<<dim3(L_/32, N_), 256, 0, stream>>>(qb, vb, kvbT, dconv_w,
                                                      pwb, proj_b, out);
}

// Round 25
// 136.361 us; speedup vs baseline: 1.0037x; 1.0037x over previous
//
#include <hip/hip_runtime.h>
#include <hip/hip_bf16.h>
#include <math.h>

#define N_ 8
#define L_ 8192
#define C_ 256
#define H_ 4
#define D_ 64
#define NH_ (N_*H_)
#define NCH 32
#define CHUNK (L_/NCH)           // 256
#define Q_ ((size_t)N_*H_*L_*D_) // 16,777,216 elements per tensor

typedef float f32x4 __attribute__((ext_vector_type(4)));
typedef short short8 __attribute__((ext_vector_type(8)));

// bf16 helpers ---------------------------------------------------------------
__device__ inline ushort f2b(float f){
  uint x = __float_as_uint(f);
  uint r = (x + 0x7fffu + ((x >> 16) & 1u)) >> 16;
  return (ushort)r;
}
__device__ inline ushort f2b_hw(float f){
  __hip_bfloat16 h = __float2bfloat16(f);
  return *reinterpret_cast<ushort*>(&h);
}
__device__ inline float b2f(ushort u){
  return __uint_as_float(((uint)u) << 16);
}
__device__ inline uint pk2h(float a, float b){
  return (uint)f2b_hw(a) | ((uint)f2b_hw(b) << 16);
}

#define GLD16(g, l) __builtin_amdgcn_global_load_lds( \
    (const __attribute__((address_space(1))) void*)(g), \
    (__attribute__((address_space(3))) void*)(l), 16, 0, 0)

// ---------------------------------------------------------------------------
// K0: fp32 -> bf16 convert for BOTH weight matrices in one launch.
// ---------------------------------------------------------------------------
__global__ __launch_bounds__(256) void conv_both(const float* __restrict__ w1,
                                                 ushort* __restrict__ wb1,
                                                 const float* __restrict__ w2,
                                                 ushort* __restrict__ wb2) {
  const int b = blockIdx.x;
  const float* src; ushort* dst; int i;
  if (b < 192) { src = w1; dst = wb1; i = (b*256 + threadIdx.x) * 4; }
  else         { src = w2; dst = wb2; i = ((b-192)*256 + threadIdx.x) * 4; }
  float4 f = *(const float4*)(src + i);
  *(ushort4*)&dst[i] = make_ushort4(f2b(f.x), f2b(f.y), f2b(f.z), f2b(f.w));
}

// ---------------------------------------------------------------------------
// K1: qkv = x @ wb^T via bf16 MFMA (best-measured version, banked; 84 us).
// BM=128, BN=256, 8 waves (2M x 4N); fused fp32->bf16 A reg-staging with
// one-iteration prefetch; B via global_load_lds (rule-21 swizzle);
// XCD-chunked 1-D grid (1536 = 512 m-tiles x 3); verified epilogue.
// Measured worse: BN/2 (94), BM/2 (126), split-cvt (+20 e2e), barrier-free
// (104), LDS epilogue (+15%), setprio (+8), prefetch variants null.
// ---------------------------------------------------------------------------
__global__ __launch_bounds__(512) void qkv_gemm_mfma2(const float* __restrict__ x,
                                                      const ushort* __restrict__ wb,
                                                      const int* __restrict__ mask,
                                                      ushort* __restrict__ qb,
                                                      ushort* __restrict__ kb,
                                                      ushort* __restrict__ vb) {
  __shared__ ushort As[128][64];
  __shared__ ushort Bs[256][64];
  const int tid  = threadIdx.x;
  const int lane = tid & 63;
  const int wid  = tid >> 6, wm = wid >> 2, wn = wid & 3;
  const int r15  = lane & 15, kg = lane >> 4;
  const int lrow8 = lane >> 3;
  const int lgrp  = lane & 7;
  const int bid = blockIdx.x;
  const int wg  = (bid & 7)*192 + (bid >> 3);   // bijective XCD chunk swizzle
  const int bx  = wg / 3, by = wg % 3;
  const int gm0 = bx * 128;
  const int gn0 = by * 256;

  const int arow = tid >> 2;              // 0..127
  const int ag0  = (tid & 3) << 1;        // first 8-col group: 0,2,4,6
  const float* asrc = x + (size_t)(gm0 + arow)*C_ + (ag0 << 3);

  f32x4 acc[4][4] = {};

  float4 cf0 = *(const float4*)(asrc);
  float4 cf1 = *(const float4*)(asrc + 4);
  float4 cf2 = *(const float4*)(asrc + 8);
  float4 cf3 = *(const float4*)(asrc + 12);

#pragma unroll
  for (int k0 = 0; k0 < C_; k0 += 64) {
    float4 nf0, nf1, nf2, nf3;
    if (k0 < C_ - 64) {
      nf0 = *(const float4*)(asrc + k0 + 64);
      nf1 = *(const float4*)(asrc + k0 + 68);
      nf2 = *(const float4*)(asrc + k0 + 72);
      nf3 = *(const float4*)(asrc + k0 + 76);
    }
    if (k0) __syncthreads();
#pragma unroll
    for (int r = 0; r < 4; ++r) {
      const int row = wid*32 + r*8 + lrow8;
      const int gc  = k0 + ((lgrp ^ (row & 7)) << 3);
      GLD16(wb + (size_t)(gn0 + row)*C_ + gc, &Bs[wid*32 + r*8][0]);
    }
    {
      uint4 p0 = make_uint4(pk2h(cf0.x,cf0.y), pk2h(cf0.z,cf0.w),
                            pk2h(cf1.x,cf1.y), pk2h(cf1.z,cf1.w));
      uint4 p1 = make_uint4(pk2h(cf2.x,cf2.y), pk2h(cf2.z,cf2.w),
                            pk2h(cf3.x,cf3.y), pk2h(cf3.z,cf3.w));
      *(uint4*)&As[arow][( ag0      ^ (arow & 7)) << 3] = p0;
      *(uint4*)&As[arow][((ag0 + 1) ^ (arow & 7)) << 3] = p1;
    }
    __syncthreads();
#pragma unroll
    for (int ks = 0; ks < 2; ++ks) {
      short8 a[4], b[4];
#pragma unroll
      for (int mi = 0; mi < 4; ++mi) {
        const int row = wm*64 + mi*16 + r15;
        a[mi] = *(const short8*)&As[row][((ks*4 + kg) ^ (row & 7)) << 3];
      }
#pragma unroll
      for (int ni = 0; ni < 4; ++ni) {
        const int row = wn*64 + ni*16 + r15;
        b[ni] = *(const short8*)&Bs[row][((ks*4 + kg) ^ (row & 7)) << 3];
      }
#pragma unroll
      for (int mi = 0; mi < 4; ++mi)
#pragma unroll
        for (int ni = 0; ni < 4; ++ni)
          acc[mi][ni] = __builtin_amdgcn_mfma_f32_16x16x32_bf16(
              a[mi], b[ni], acc[mi][ni], 0, 0, 0);
    }
    if (k0 < C_ - 64) { cf0 = nf0; cf1 = nf1; cf2 = nf2; cf3 = nf3; }
  }

  const int sh = by*4 + wn;
  const int s = sh >> 2, h = sh & 3;
  ushort* dst = (s == 0) ? qb : (s == 1) ? kb : vb;
#pragma unroll
  for (int mi = 0; mi < 4; ++mi) {
    const int rbase = gm0 + wm*64 + mi*16 + (kg << 2);
#pragma unroll
    for (int j = 0; j < 4; ++j) {
      const int gr = rbase + j;
      const int nn = gr >> 13, l = gr & (L_-1);
      float v0 = acc[mi][0][j], v1 = acc[mi][1][j],
            v2 = acc[mi][2][j], v3 = acc[mi][3][j];
      if (s < 2) {
        float ss = v0*v0 + v1*v1 + v2*v2 + v3*v3;
        ss += __shfl_xor(ss, 1); ss += __shfl_xor(ss, 2);
        ss += __shfl_xor(ss, 4); ss += __shfl_xor(ss, 8);
        const float inv = 1.0f / sqrtf(ss);
        v0 *= inv; v1 *= inv; v2 *= inv; v3 *= inv;
      }
      const bool masked = (s == 0) && (mask[(size_t)nn*L_ + l] == 0);
      const size_t base = (((size_t)nn*H_ + h)*L_ + l)*D_ + r15;
      if (masked) {
        const ushort mb = 0xBE00u;  // bf16(-0.125)
        dst[base] = mb; dst[base+16] = mb; dst[base+32] = mb; dst[base+48] = mb;
      } else {
        dst[base]    = f2b(v0); dst[base+16] = f2b(v1);
        dst[base+32] = f2b(v2); dst[base+48] = f2b(v3);
      }
    }
  }
}

// ---------------------------------------------------------------------------
// K3 (MFMA): per (n,h,chunk): kv[d][e] = sum_l k[l][d] v[l][e].
// ---------------------------------------------------------------------------
__global__ __launch_bounds__(256, 8) void kv_partial(const ushort* __restrict__ kb,
                                                     const ushort* __restrict__ vb,
                                                     ushort* __restrict__ part) {
  const int nh = blockIdx.x, ch = blockIdx.y;
  const size_t base = ((size_t)nh*L_ + (size_t)ch*CHUNK) * 64;
  __shared__ ushort ks[32][68];
  __shared__ ushort vs[32][68];
  const int tid = threadIdx.x;
  const int lane = tid & 63;
  const int w = tid >> 6;
  const int r15 = lane & 15, kg = lane >> 4;
  const int lr = tid >> 3, lc = (tid & 7) << 3;
  f32x4 acc[4] = {};

  for (int l0 = 0; l0 < CHUNK; l0 += 32) {
    if (l0) __syncthreads();
    *(uint4*)&ks[lr][lc] = *(const uint4*)(kb + base + (size_t)(l0+lr)*64 + lc);
    *(uint4*)&vs[lr][lc] = *(const uint4*)(vb + base + (size_t)(l0+lr)*64 + lc);
    __syncthreads();
    short8 a;
#pragma unroll
    for (int j = 0; j < 8; ++j) a[j] = (short)ks[kg*8 + j][w*16 + r15];
#pragma unroll
    for (int ni = 0; ni < 4; ++ni) {
      short8 b;
#pragma unroll
      for (int j = 0; j < 8; ++j) b[j] = (short)vs[kg*8 + j][ni*16 + r15];
      acc[ni] = __builtin_amdgcn_mfma_f32_16x16x32_bf16(a, b, acc[ni], 0, 0, 0);
    }
  }
  ushort* P = part + ((size_t)nh*NCH + ch)*4096;
#pragma unroll
  for (int ni = 0; ni < 4; ++ni)
#pragma unroll
    for (int j = 0; j < 4; ++j)
      P[(w*16 + kg*4 + j)*64 + ni*16 + r15] = f2b(acc[ni][j]);
}

// ---------------------------------------------------------------------------
// K4: reduce bf16 partials (fp32 accum), fold 1/pi, write kvbT[e][d] bf16.
// ---------------------------------------------------------------------------
__global__ __launch_bounds__(256) void kv_reduce(const ushort* __restrict__ part,
                                                 ushort* __restrict__ kvbT) {
  const int nh = blockIdx.x;
  const int i0 = blockIdx.y*1024 + threadIdx.x*4;
  float s0 = 0.f, s1 = 0.f, s2 = 0.f, s3 = 0.f;
#pragma unroll
  for (int c = 0; c < NCH; ++c) {
    ushort4 p = *(const ushort4*)(part + ((size_t)nh*NCH + c)*4096 + i0);
    s0 += b2f(p.x); s1 += b2f(p.y); s2 += b2f(p.z); s3 += b2f(p.w);
  }
  const float ip = 0.31830988618379067f;
  const float r[4] = {s0*ip, s1*ip, s2*ip, s3*ip};
#pragma unroll
  for (int j = 0; j < 4; ++j) {
    const int i = i0 + j;
    const int d = i >> 6, e = i & 63;
    kvbT[(size_t)nh*4096 + e*64 + d] = f2b(r[j]);
  }
}

// ---------------------------------------------------------------------------
// K5: MFMA attn+proj, 32-row tiles (best-measured version, banked).
// ---------------------------------------------------------------------------
__global__ __launch_bounds__(256, 4) void attn_proj3(const ushort* __restrict__ qb,
                                                     const ushort* __restrict__ vb,
                                                     const ushort* __restrict__ kvbT,
                                                     const float* __restrict__ dwc,
                                                     const ushort* __restrict__ pwb,
                                                     const float* __restrict__ pb,
                                                     float* __restrict__ out) {
  __shared__ ushort vsm[4][40][72];   // 23040 B (rows l0-4 .. l0+35)
  __shared__ ushort attn_s[32][260];  // 16640 B
  const int tid = threadIdx.x;
  const int lane = tid & 63;
  const int w = tid >> 6;
  const int r15 = lane & 15, kg = lane >> 4;
  const int n = blockIdx.y;
  const int l0 = blockIdx.x * 32;

  for (int f = tid; f < 1280; f += 256) {
    const int h = f / 320, rem = f % 320;
    const int row = rem >> 3, c0 = (rem & 7) << 3;
    const int lg = l0 - 4 + row;
    uint4 val = make_uint4(0,0,0,0);
    if ((unsigned)lg < (unsigned)L_)
      val = *(const uint4*)(vb + (((size_t)(n*4+h)*L_ + lg) << 6) + c0);
    *(uint4*)&vsm[h][row][c0] = val;
  }

  const int nh = n*4 + w;
  f32x4 acc[2][4] = {};
  {
    const ushort* qbase = qb + ((size_t)nh*L_ + l0)*64;
    const ushort* kvb = kvbT + (size_t)nh*4096;
#pragma unroll
    for (int ks = 0; ks < 2; ++ks) {
      const int kofs = ks*32 + kg*8;
      short8 a[2], b[4];
#pragma unroll
      for (int mi = 0; mi < 2; ++mi)
        a[mi] = *(const short8*)(qbase + (size_t)(mi*16 + r15)*64 + kofs);
#pragma unroll
      for (int ni = 0; ni < 4; ++ni)
        b[ni] = *(const short8*)(kvb + (ni*16 + r15)*64 + kofs);
#pragma unroll
      for (int mi = 0; mi < 2; ++mi)
#pragma unroll
        for (int ni = 0; ni < 4; ++ni)
          acc[mi][ni] = __builtin_amdgcn_mfma_f32_16x16x32_bf16(
              a[mi], b[ni], acc[mi][ni], 0, 0, 0);
    }
  }
  __syncthreads();   // vsm staged

  {
    float wcv[9];
#pragma unroll
    for (int j = 0; j < 9; ++j) wcv[j] = dwc[w*9 + j];
    float win[9];
#pragma unroll
    for (int j = 0; j < 9; ++j) win[j] = b2f(vsm[w][j][lane]);
#pragma unroll
    for (int r = 0; r < 32; ++r) {
      float cv = 0.f;
#pragma unroll
      for (int j = 0; j < 9; ++j) cv += win[j] * wcv[j];
      attn_s[r][w*64 + lane] = f2b(cv);
      if (r < 31) {
#pragma unroll
        for (int j = 0; j < 8; ++j) win[j] = win[j+1];
        win[8] = b2f(vsm[w][r + 9][lane]);
      }
    }
  }
  // NO barrier: norm phase touches only this wave's own attn_s columns.

#pragma unroll
  for (int mi = 0; mi < 2; ++mi) {
#pragma unroll
    for (int j = 0; j < 4; ++j) {
      const int r = mi*16 + kg*4 + j;
      float t[4];
#pragma unroll
      for (int ni = 0; ni < 4; ++ni) {
        const int e = ni*16 + r15;
        t[ni] = acc[mi][ni][j] + 0.5f * b2f(vsm[w][r+4][e]);
      }
      float ss = t[0]*t[0] + t[1]*t[1] + t[2]*t[2] + t[3]*t[3];
      ss += __shfl_xor(ss, 1); ss += __shfl_xor(ss, 2);
      ss += __shfl_xor(ss, 4); ss += __shfl_xor(ss, 8);
      const float inv = 1.0f / sqrtf(ss);
#pragma unroll
      for (int ni = 0; ni < 4; ++ni) {
        const int e = ni*16 + r15;
        const float cv = b2f(attn_s[r][w*64 + e]);
        attn_s[r][w*64 + e] = f2b(t[ni]*inv + cv);
      }
    }
  }
  __syncthreads();   // attn tile final

  f32x4 acc2[2][4] = {};
  const ushort* pwq = pwb + (size_t)(w*64)*256;
#pragma unroll
  for (int ks = 0; ks < 8; ++ks) {
    const int kofs = ks*32 + kg*8;
    short8 a[2], b[4];
#pragma unroll
    for (int mi = 0; mi < 2; ++mi)
      a[mi] = *(const short8*)&attn_s[mi*16 + r15][kofs];
#pragma unroll
    for (int ni = 0; ni < 4; ++ni)
      b[ni] = *(const short8*)(pwq + (size_t)(ni*16 + r15)*256 + kofs);
#pragma unroll
    for (int mi = 0; mi < 2; ++mi)
#pragma unroll
      for (int ni = 0; ni < 4; ++ni)
        acc2[mi][ni] = __builtin_amdgcn_mfma_f32_16x16x32_bf16(
            a[mi], b[ni], acc2[mi][ni], 0, 0, 0);
  }
#pragma unroll
  for (int ni = 0; ni < 4; ++ni) {
    const int o = w*64 + ni*16 + r15;
    const float bias = pb[o];
#pragma unroll
    for (int mi = 0; mi < 2; ++mi) {
#pragma unroll
      for (int j = 0; j < 4; ++j) {
        const int l = l0 + mi*16 + kg*4 + j;
        out[((size_t)n*L_ + l)*C_ + o] = acc2[mi][ni][j] + bias;
      }
    }
  }
}

extern "C" void kernel_launch(void* const* d_in, const int* in_sizes, int n_in,
                              void* d_out, int out_size, void* d_ws, size_t ws_size,
                              hipStream_t stream) {
  const float* x      = (const float*)d_in[0];
  const int*   mask   = (const int*)d_in[1];
  const float* qkv_w  = (const float*)d_in[2];
  const float* proj_w = (const float*)d_in[3];
  const float* proj_b = (const float*)d_in[4];
  const float* dconv_w= (const float*)d_in[5];
  float* out = (float*)d_out;

  // ws: q/k/v bf16 (96 MB) + part bf16 (8 MB) + weights (<1 MB)
  ushort* qb = (ushort*)d_ws;
  ushort* kb = qb + Q_;
  ushort* vb = kb + Q_;
  ushort* part = vb + Q_;                          // NH_*NCH*4096 bf16 = 8 MB
  ushort* kvbT = part + (size_t)NH_*NCH*4096;
  ushort* wb   = kvbT + (size_t)NH_*4096;
  ushort* pwb  = wb + 768*256;

  conv_both     <<<dim3(256),       256, 0, stream>>>(qkv_w, wb, proj_w, pwb);
  qkv_gemm_mfma2<<<dim3(1536),      512, 0, stream>>>(x, wb, mask, qb, kb, vb);
  kv_partial    <<<dim3(NH_, NCH),  256, 0, stream>>>(kb, vb, part);
  kv_reduce     <<<dim3(NH_, 4),    256, 0, stream>>>(part, kvbT);
  attn_proj3    <<<dim3(L_/32, N_), 256, 0, stream>>>(qb, vb, kvbT, dconv_w,
                                                      pwb, proj_b, out);
}